// Round 1
// baseline (1677.729 us; speedup 1.0000x reference)
//
#include <hip/hip_runtime.h>
#include <math.h>

#define HH 512
#define LL 128
#define BB 4
#define TT 130            // L + 2
#define G4 2048           // 4*H

// ---- ws layout (float indices) ----
// HF: (TT+1) slots of [B][H] = 131*2048 = 268288 floats   (HF[s] = fwd state after consuming xs[0..s-1])
// HB: 268288 floats                                       (HB[s] = bwd state after consuming xs[s..T-1])
// cnt: 2*131 ints (cntF then cntB)
#define HF_OFF 0
#define HB_OFF 268288
#define CNT_OFF 536576
// xproj lives in the TAIL of d_out (K3 overwrites it last): 2 * 130*4*2048 floats
#define XPROJ_PER_DIR (TT * BB * G4)          // 1064960
#define XPROJ_OFF (67108864 - 2 * XPROJ_PER_DIR)  // 64978944

// ---------------- K0: zero init of state slots + counters ----------------
__global__ __launch_bounds__(256) void k0_init(float* ws) {
    int tid = threadIdx.x;
    float* HF = ws + HF_OFF;
    float* HB = ws + HB_OFF;
    int* cnt = (int*)(ws + CNT_OFF);
    for (int i = tid; i < G4; i += 256) {
        HF[i] = 0.f;                 // HF[0]
        HB[(size_t)TT * G4 + i] = 0.f; // HB[T]
    }
    for (int i = tid; i < 2 * 131; i += 256) cnt[i] = 0;
}

// ---------------- K1: input projection GEMM (both dirs) ----------------
// xproj[d][t][b][n] = x[t][b][:] . W_ih[n][:] + bias[n];  x[0]=x[T-1]=0
__global__ __launch_bounds__(256) void k1_xproj(
    const float* __restrict__ wr,
    const float* __restrict__ WihF, const float* __restrict__ bF,
    const float* __restrict__ WihB, const float* __restrict__ bB,
    float* __restrict__ outbuf) {
    __shared__ float As[16][132];
    __shared__ float Bs[16][132];
    int bid = blockIdx.x;
    int d = bid / 80;
    int r2 = bid % 80;
    int mt = r2 >> 4, nt = r2 & 15;
    const float* Wih  = d ? WihB : WihF;
    const float* bias = d ? bB : bF;
    float* xp = outbuf + XPROJ_OFF + (size_t)d * XPROJ_PER_DIR;
    int tid = threadIdx.x;
    int ty = tid >> 4, tx = tid & 15;
    int m0 = mt * 128, n0 = nt * 128;

    float acc[8][8];
#pragma unroll
    for (int i = 0; i < 8; i++)
#pragma unroll
        for (int j = 0; j < 8; j++) acc[i][j] = 0.f;

    for (int k0 = 0; k0 < HH; k0 += 16) {
#pragma unroll
        for (int l = tid; l < 512; l += 256) {
            int rrow = l & 127;
            int kq = l >> 7;
            int m = m0 + rrow;
            int t = m >> 2, b = m & 3;
            float4 av = make_float4(0.f, 0.f, 0.f, 0.f);
            if (t >= 1 && t <= 128)
                av = *(const float4*)&wr[((size_t)b * LL + (t - 1)) * HH + k0 + kq * 4];
            As[kq * 4 + 0][rrow] = av.x;
            As[kq * 4 + 1][rrow] = av.y;
            As[kq * 4 + 2][rrow] = av.z;
            As[kq * 4 + 3][rrow] = av.w;
            float4 bv = *(const float4*)&Wih[(size_t)(n0 + rrow) * HH + k0 + kq * 4];
            Bs[kq * 4 + 0][rrow] = bv.x;
            Bs[kq * 4 + 1][rrow] = bv.y;
            Bs[kq * 4 + 2][rrow] = bv.z;
            Bs[kq * 4 + 3][rrow] = bv.w;
        }
        __syncthreads();
#pragma unroll
        for (int kk = 0; kk < 16; kk++) {
            float4 a0 = *(const float4*)&As[kk][ty * 8];
            float4 a1 = *(const float4*)&As[kk][ty * 8 + 4];
            float4 b0 = *(const float4*)&Bs[kk][tx * 8];
            float4 b1 = *(const float4*)&Bs[kk][tx * 8 + 4];
            float am[8] = {a0.x, a0.y, a0.z, a0.w, a1.x, a1.y, a1.z, a1.w};
            float bn[8] = {b0.x, b0.y, b0.z, b0.w, b1.x, b1.y, b1.z, b1.w};
#pragma unroll
            for (int i = 0; i < 8; i++)
#pragma unroll
                for (int j = 0; j < 8; j++) acc[i][j] = fmaf(am[i], bn[j], acc[i][j]);
        }
        __syncthreads();
    }
    float4 bv0 = *(const float4*)&bias[n0 + tx * 8];
    float4 bv1 = *(const float4*)&bias[n0 + tx * 8 + 4];
#pragma unroll
    for (int i = 0; i < 8; i++) {
        int m = m0 + ty * 8 + i;
        if (m < TT * BB) {
            float4 o0 = make_float4(acc[i][0] + bv0.x, acc[i][1] + bv0.y,
                                    acc[i][2] + bv0.z, acc[i][3] + bv0.w);
            float4 o1 = make_float4(acc[i][4] + bv1.x, acc[i][5] + bv1.y,
                                    acc[i][6] + bv1.z, acc[i][7] + bv1.w);
            *(float4*)&xp[(size_t)m * G4 + n0 + tx * 8] = o0;
            *(float4*)&xp[(size_t)m * G4 + n0 + tx * 8 + 4] = o1;
        }
    }
}

__device__ __forceinline__ float sigm_(float x) { return 1.f / (1.f + __expf(-x)); }
__device__ __forceinline__ float tanh_(float x) {
    float xc = fminf(fmaxf(x, -15.f), 15.f);
    float e = __expf(-2.f * xc);
    return (1.f - e) / (1.f + e);
}

// ---------------- K2: persistent bidirectional LSTM recurrence ----------------
// 64 blocks: blocks 0..31 forward, 32..63 backward. Block g owns 16 hidden
// units j0=g*16 (=> 64 rows of W_hh: 4 gates x 16 units), register-resident.
__global__ __launch_bounds__(256, 1) void k2_lstm(
    const float* __restrict__ WhhF, const float* __restrict__ WhhB,
    const float* __restrict__ outbuf, float* __restrict__ ws) {
    __shared__ float4 hlds4[512];     // h staged, XOR-swizzled f4 layout
    __shared__ float g_lds[64][4];
    __shared__ float clds[16][4];

    int bid = blockIdx.x;
    int dir = bid >> 5;
    int g = bid & 31;
    int j0 = g * 16;
    const float* Whh = dir ? WhhB : WhhF;
    const float* xp = outbuf + XPROJ_OFF + (size_t)dir * XPROJ_PER_DIR;
    float* Hbase = ws + (dir ? HB_OFF : HF_OFF);
    int* cnt = (int*)(ws + CNT_OFF) + dir * 131;
    int tid = threadIdx.x;
    int rg = tid >> 5, cc = tid & 31;  // 8 row-groups x 32 col-chunks

    // ---- load weights: thread owns 8 rows x 16 cols of its block's 64x512 slice
    float w[8][16];
#pragma unroll
    for (int i = 0; i < 8; i++) {
        int rl = rg * 8 + i;
        int q = rl >> 4, u = rl & 15;
        const float* wrow = Whh + (size_t)(q * 512 + j0 + u) * HH + cc * 16;
#pragma unroll
        for (int c4 = 0; c4 < 4; c4++) {
            float4 v = *(const float4*)&wrow[c4 * 4];
            w[i][c4 * 4 + 0] = v.x;
            w[i][c4 * 4 + 1] = v.y;
            w[i][c4 * 4 + 2] = v.z;
            w[i][c4 * 4 + 3] = v.w;
        }
    }

    int u_ = (tid >> 2) & 15, b_ = tid & 3;  // combine-thread mapping (tid<64)

    for (int s = 0; s < TT; s++) {
        int t = dir ? (129 - s) : s;
        int slot_in = dir ? (t + 1) : t;
        int slot_out = dir ? t : (t + 1);

        // prefetch xproj gates (independent of h) — hides LLC latency under spin/dot
        float xq[4] = {0.f, 0.f, 0.f, 0.f};
        if (tid < 64) {
#pragma unroll
            for (int q = 0; q < 4; q++)
                xq[q] = xp[((size_t)t * BB + b_) * G4 + q * 512 + j0 + u_];
        }

        if (s > 0) {
            if (tid == 0) {
                while (__hip_atomic_load(&cnt[slot_in], __ATOMIC_RELAXED,
                                         __HIP_MEMORY_SCOPE_AGENT) < 32) {}
            }
            __syncthreads();
            __threadfence();  // acquire: invalidate stale cache before reading h
        }

        // ---- stage h (2048 f) into LDS, XOR-swizzled to kill 16-way conflicts
        const float4* hsrc = (const float4*)(Hbase + (size_t)slot_in * G4);
#pragma unroll
        for (int l = tid; l < 512; l += 256) {
            int brow = l >> 7;
            int quad = l & 127;
            int qs = quad ^ ((quad >> 2) & 7);
            hlds4[brow * 128 + qs] = hsrc[l];
        }
        __syncthreads();

        // ---- dot: p[i][b] = sum over this thread's 16 cols
        float p[8][4];
#pragma unroll
        for (int i = 0; i < 8; i++)
#pragma unroll
            for (int b = 0; b < 4; b++) p[i][b] = 0.f;
#pragma unroll
        for (int b = 0; b < 4; b++) {
#pragma unroll
            for (int c4 = 0; c4 < 4; c4++) {
                int quad = cc * 4 + c4;
                int qs = quad ^ (cc & 7);  // == quad ^ ((quad>>2)&7)
                float4 h4 = hlds4[b * 128 + qs];
#pragma unroll
                for (int i = 0; i < 8; i++) {
                    p[i][b] = fmaf(w[i][c4 * 4 + 0], h4.x, p[i][b]);
                    p[i][b] = fmaf(w[i][c4 * 4 + 1], h4.y, p[i][b]);
                    p[i][b] = fmaf(w[i][c4 * 4 + 2], h4.z, p[i][b]);
                    p[i][b] = fmaf(w[i][c4 * 4 + 3], h4.w, p[i][b]);
                }
            }
        }
        // ---- reduce over 32 col-chunks (lanes within 32-group)
#pragma unroll
        for (int m = 1; m < 32; m <<= 1) {
#pragma unroll
            for (int i = 0; i < 8; i++)
#pragma unroll
                for (int b = 0; b < 4; b++) p[i][b] += __shfl_xor(p[i][b], m, 64);
        }
        if (cc == 0) {
#pragma unroll
            for (int i = 0; i < 8; i++)
#pragma unroll
                for (int b = 0; b < 4; b++) g_lds[rg * 8 + i][b] = p[i][b];
        }
        __syncthreads();

        // ---- gates + state update (64 threads: 16 units x 4 batches)
        if (tid < 64) {
            float gv[4];
#pragma unroll
            for (int q = 0; q < 4; q++) gv[q] = g_lds[q * 16 + u_][b_] + xq[q];
            float cprev = (s == 0) ? 0.f : clds[u_][b_];
            float si = sigm_(gv[0]);
            float sf = sigm_(gv[1]);
            float tg = tanh_(gv[2]);
            float so = sigm_(gv[3]);
            float cn = sf * cprev + si * tg;
            clds[u_][b_] = cn;
            Hbase[(size_t)slot_out * G4 + b_ * HH + j0 + u_] = so * tanh_(cn);
        }
        __syncthreads();
        if (tid == 0) {
            __threadfence();  // release: push h slice to device visibility
            __hip_atomic_fetch_add(&cnt[slot_out], 1, __ATOMIC_RELEASE,
                                   __HIP_MEMORY_SCOPE_AGENT);
        }
    }
}

// ---------------- K3: pairwise span diffs -> output ----------------
// out[i][k][b][c] : c<512 -> HF[k+1]-HF[i+1] ; c>=512 -> HB[i+1]-HB[k+1]; masked
__global__ __launch_bounds__(256) void k3_out(const float* __restrict__ ws,
                                              float* __restrict__ out) {
    const float* HF = ws + HF_OFF;
    const float* HB = ws + HB_OFF;
    size_t idx = (size_t)blockIdx.x * 256 + threadIdx.x;
    const size_t total = 16777216;  // f4 count
    const size_t stride = (size_t)2048 * 256;
    for (; idx < total; idx += stride) {
        int c4 = idx & 255;
        int b = (idx >> 8) & 3;
        int k = (idx >> 10) & 127;
        int i = (int)(idx >> 17);
        float4 res = make_float4(0.f, 0.f, 0.f, 0.f);
        if (i >= 1 && k > i && k <= 126) {
            int c0 = c4 * 4;
            if (c0 < 512) {
                float4 a = *(const float4*)&HF[(size_t)(k + 1) * G4 + b * HH + c0];
                float4 c = *(const float4*)&HF[(size_t)(i + 1) * G4 + b * HH + c0];
                res = make_float4(a.x - c.x, a.y - c.y, a.z - c.z, a.w - c.w);
            } else {
                int cd = c0 - 512;
                float4 a = *(const float4*)&HB[(size_t)(i + 1) * G4 + b * HH + cd];
                float4 c = *(const float4*)&HB[(size_t)(k + 1) * G4 + b * HH + cd];
                res = make_float4(a.x - c.x, a.y - c.y, a.z - c.z, a.w - c.w);
            }
        }
        *(float4*)&out[idx * 4] = res;
    }
}

extern "C" void kernel_launch(void* const* d_in, const int* in_sizes, int n_in,
                              void* d_out, int out_size, void* d_ws, size_t ws_size,
                              hipStream_t stream) {
    const float* wr   = (const float*)d_in[0];
    const float* WihF = (const float*)d_in[1];
    const float* WhhF = (const float*)d_in[2];
    const float* bF   = (const float*)d_in[3];
    const float* WihB = (const float*)d_in[4];
    const float* WhhB = (const float*)d_in[5];
    const float* bB   = (const float*)d_in[6];
    float* out = (float*)d_out;
    float* ws = (float*)d_ws;

    k0_init<<<1, 256, 0, stream>>>(ws);
    k1_xproj<<<160, 256, 0, stream>>>(wr, WihF, bF, WihB, bB, out);
    k2_lstm<<<64, 256, 0, stream>>>(WhhF, WhhB, out, ws);
    k3_out<<<2048, 256, 0, stream>>>(ws, out);
}